// Round 4
// baseline (3148.595 us; speedup 1.0000x reference)
//
#include <hip/hip_runtime.h>
#include <cstddef>

#define T_STEPS 512
#define BATCH   64
#define EDIM    512
#define HDIM    512
#define ODIM    512

#define HALF    256       // columns per scan block (2 blocks per cluster)
#define HPAD    520       // h LDS row stride (bf16): 16B-aligned, breaks pow2

typedef __bf16 bf16;
typedef __bf16 bf16x8 __attribute__((ext_vector_type(8)));
typedef float  f32x4  __attribute__((ext_vector_type(4)));

// ---------------------------------------------------------------------------
// Parallel GEMM: C[r,n] = sum_k X[r*ldx+k] * W[n*ldw+kw0+k] + bias[n]
// (round-2 proven; MFMA-ize next round)
// ---------------------------------------------------------------------------
template <typename XT>
__global__ __launch_bounds__(256) void gemm_bias_kernel(
    const XT* __restrict__ X, int ldx,
    const float* __restrict__ W, int ldw, int kw0,
    const float* __restrict__ bias,
    float* __restrict__ C, int ldc, int K)
{
  __shared__ float Xs[64][65];
  __shared__ float Ws[64][65];
  const int tid  = threadIdx.x;
  const int row0 = blockIdx.x * 64;
  const int col0 = blockIdx.y * 64;
  const int tx = tid & 15, ty = tid >> 4;
  float acc[4][4] = {};

  for (int k0 = 0; k0 < K; k0 += 64) {
#pragma unroll
    for (int i = 0; i < 16; ++i) {
      int idx = tid + i * 256;
      int r = idx >> 6, c = idx & 63;
      Xs[r][c] = (float)X[(size_t)(row0 + r) * ldx + k0 + c];
      Ws[r][c] = W[(size_t)(col0 + r) * ldw + kw0 + k0 + c];
    }
    __syncthreads();
#pragma unroll
    for (int kk = 0; kk < 64; ++kk) {
      float a[4], b[4];
#pragma unroll
      for (int i = 0; i < 4; ++i) a[i] = Xs[ty * 4 + i][kk];
#pragma unroll
      for (int j = 0; j < 4; ++j) b[j] = Ws[tx * 4 + j][kk];
#pragma unroll
      for (int i = 0; i < 4; ++i)
#pragma unroll
        for (int j = 0; j < 4; ++j) acc[i][j] += a[i] * b[j];
    }
    __syncthreads();
  }

#pragma unroll
  for (int i = 0; i < 4; ++i) {
    size_t r = (size_t)(row0 + ty * 4 + i);
#pragma unroll
    for (int j = 0; j < 4; ++j) {
      int n = col0 + tx * 4 + j;
      C[r * ldc + n] = acc[i][j] + bias[n];
    }
  }
}

// ---------------------------------------------------------------------------
// Scan: grid = 8 blocks x 512 threads. Block (c = bid>>1, s = bid&1) owns
// batch rows 16c..16c+15 and output cols s*256..s*256+255.
// W slice (512 x 256 bf16 = 256 KB): kt 0..1 in LDS (32 KB), kt 2..15 in
// 112 VGPRs/lane. Per step: exchange h halves with partner block via global
// Hbf + round-2-proven release/acquire flag; MFMA over full K=512 from hsm.
// Fragment layouts (verified round 2 on this HW):
//   A-frag: A[m=lane&15][k=(lane>>4)*8+j]; B-frag: B[k=(lane>>4)*8+j][n=lane&15]
//   D: row=(lane>>4)*4+r, col=lane&15
// ---------------------------------------------------------------------------
__global__ __launch_bounds__(512) void scan_kernel(
    const float* __restrict__ A,     // [B*T, H] fp32, row = b*T + t
    const float* __restrict__ W1,    // [H, E+H] fp32
    bf16* __restrict__ Hbf,          // [B*T, H] bf16
    int* __restrict__ flags)         // 8 flags, 32-int stride
{
  __shared__ __align__(16) bf16 Wlds[16 * 2 * 64 * 8];  // 32 KB: kt 0..1
  __shared__ __align__(16) bf16 hsm[16 * HPAD];         // 16.6 KB: h_{t-1}/h_t

  const int tid   = threadIdx.x;
  const int bid   = blockIdx.x;
  const int c     = bid >> 1;
  const int s     = bid & 1;
  const int col0  = s * HALF;
  const int pcol0 = (1 - s) * HALF;
  const int rb0   = c * 16;
  const int w     = tid >> 6, lane = tid & 63;
  const int q     = lane >> 4, nl = lane & 15;

  // ---- one-time: W ksteps 0..1 -> LDS (16 tiles x 2 kt x 64 lanes) -------
  for (int idx = tid; idx < 16 * 2 * 64; idx += 512) {
    int l  = idx & 63;
    int kt = (idx >> 6) & 1;
    int tg = idx >> 7;
    int n  = col0 + tg * 16 + (l & 15);
    int k  = kt * 32 + (l >> 4) * 8;
    const float* src = W1 + (size_t)n * (EDIM + HDIM) + EDIM + k;
    bf16x8 v;
#pragma unroll
    for (int u = 0; u < 8; ++u) v[u] = (bf16)src[u];
    *(bf16x8*)&Wlds[(size_t)idx * 8] = v;
  }

  // ---- one-time: W ksteps 2..15 -> registers (2 tiles x 14 kt) -----------
  bf16x8 Wreg[2][14];
#pragma unroll
  for (int i = 0; i < 2; ++i) {
    int n = col0 + w * 32 + i * 16 + nl;
    const float* wrow = W1 + (size_t)n * (EDIM + HDIM) + EDIM;
#pragma unroll
    for (int kt2 = 0; kt2 < 14; ++kt2) {
      const float* src = wrow + (kt2 + 2) * 32 + q * 8;
      bf16x8 v;
#pragma unroll
      for (int u = 0; u < 8; ++u) v[u] = (bf16)src[u];
      Wreg[i][kt2] = v;
    }
  }
  __syncthreads();

  int* myflag = flags + (c * 2 + s) * 32;
  int* paflag = flags + (c * 2 + (1 - s)) * 32;

  // ---- A prefetch (fp32, 8 values: 2 tiles x 4 rows) ---------------------
  float Ac[2][4], An[2][4];
#pragma unroll
  for (int i = 0; i < 2; ++i)
#pragma unroll
    for (int r = 0; r < 4; ++r)
      Ac[i][r] = A[((size_t)(rb0 + q * 4 + r) * T_STEPS + 0) * HDIM
                   + col0 + w * 32 + i * 16 + nl];

  f32x4 acc[2];

  for (int t = 0; t < T_STEPS; ++t) {
    if (t > 0) {
      // ---- wait for partner's h_{t-1} (round-2 proven protocol) ----------
      if (tid == 0) {
        while (__hip_atomic_load(paflag, __ATOMIC_RELAXED,
                                 __HIP_MEMORY_SCOPE_AGENT) < t) {}
      }
      __syncthreads();                                    // B1
      __threadfence();   // acquire on every thread before partner reads
      // ---- pull partner half into hsm ------------------------------------
      int m = tid >> 5, j = tid & 31;
      bf16x8 hv = *(const bf16x8*)(
          Hbf + ((size_t)(rb0 + m) * T_STEPS + (t - 1)) * HDIM + pcol0 + j * 8);
      *(bf16x8*)&hsm[m * HPAD + pcol0 + j * 8] = hv;
    }

    // ---- acc init from prefetched A_t ------------------------------------
#pragma unroll
    for (int i = 0; i < 2; ++i)
#pragma unroll
      for (int r = 0; r < 4; ++r) acc[i][r] = Ac[i][r];

    // ---- issue A_{t+1} prefetch ------------------------------------------
    {
      int tn = (t + 1 < T_STEPS) ? t + 1 : 0;
#pragma unroll
      for (int i = 0; i < 2; ++i)
#pragma unroll
        for (int r = 0; r < 4; ++r)
          An[i][r] = A[((size_t)(rb0 + q * 4 + r) * T_STEPS + tn) * HDIM
                       + col0 + w * 32 + i * 16 + nl];
    }

    // ---- h_{t-1} @ W1h^T over full K=512 ---------------------------------
    if (t > 0) {
      __syncthreads();                                    // B2: hsm complete
#pragma unroll
      for (int kt = 0; kt < 16; ++kt) {
        bf16x8 af = *(bf16x8*)&hsm[nl * HPAD + kt * 32 + q * 8];
        if (kt < 2) {
#pragma unroll
          for (int i = 0; i < 2; ++i) {
            bf16x8 b = *(bf16x8*)&Wlds[(size_t)(((w * 2 + i) * 2 + kt) * 64 + lane) * 8];
            acc[i] = __builtin_amdgcn_mfma_f32_16x16x32_bf16(af, b, acc[i], 0, 0, 0);
          }
        } else {
#pragma unroll
          for (int i = 0; i < 2; ++i)
            acc[i] = __builtin_amdgcn_mfma_f32_16x16x32_bf16(af, Wreg[i][kt - 2], acc[i], 0, 0, 0);
        }
      }
    }

    __syncthreads();                                      // B3: hsm reads done

    // ---- relu + write own h_t half: hsm (for next step) + global ---------
#pragma unroll
    for (int i = 0; i < 2; ++i)
#pragma unroll
      for (int r = 0; r < 4; ++r) {
        float v = acc[i][r] > 0.0f ? acc[i][r] : 0.0f;
        int colg = col0 + w * 32 + i * 16 + nl;
        hsm[(q * 4 + r) * HPAD + colg] = (bf16)v;
        Hbf[((size_t)(rb0 + q * 4 + r) * T_STEPS + t) * HDIM + colg] = (bf16)v;
      }

    // ---- rotate A prefetch ----------------------------------------------
#pragma unroll
    for (int i = 0; i < 2; ++i)
#pragma unroll
      for (int r = 0; r < 4; ++r) Ac[i][r] = An[i][r];

    __syncthreads();                    // B4: per-wave vmcnt drained at barrier
    if (tid == 0) {
      __threadfence();                  // release
      __hip_atomic_fetch_add(myflag, 1, __ATOMIC_RELEASE,
                             __HIP_MEMORY_SCOPE_AGENT);
    }
  }
}

// ---------------------------------------------------------------------------
// h_final = Hbf[:, T-1, :] -> fp32 tail of d_out
// ---------------------------------------------------------------------------
__global__ __launch_bounds__(256) void copy_hfinal_kernel(
    const bf16* __restrict__ Hbf, float* __restrict__ out)
{
  int i = blockIdx.x * blockDim.x + threadIdx.x;   // 0 .. B*H-1
  int b = i / HDIM, n = i % HDIM;
  out[i] = (float)Hbf[((size_t)b * T_STEPS + (T_STEPS - 1)) * HDIM + n];
}

extern "C" void kernel_launch(void* const* d_in, const int* in_sizes, int n_in,
                              void* d_out, int out_size, void* d_ws, size_t ws_size,
                              hipStream_t stream) {
  const float* x  = (const float*)d_in[0];   // [B, T, E]
  const float* W1 = (const float*)d_in[1];   // [H, E+H]
  const float* b1 = (const float*)d_in[2];   // [H]
  const float* W2 = (const float*)d_in[3];   // [O, H]
  const float* b2 = (const float*)d_in[4];   // [O]

  float* out = (float*)d_out;
  float* A   = out;   // fp32 x-projection staged in d_out; consumed by scan
                      // before the output GEMM overwrites it

  bf16* Hbf  = (bf16*)d_ws;                                       // 32 MB
  int* flags = (int*)((char*)d_ws + (size_t)BATCH * T_STEPS * HDIM * 2);

  // 0) zero the flags (ws is poisoned 0xAA each launch)
  hipMemsetAsync(flags, 0, 8 * 32 * sizeof(int), stream);

  // 1) A = X @ W1[:, :E]^T + b1  (fp32)
  {
    dim3 grid(BATCH * T_STEPS / 64, HDIM / 64);
    gemm_bias_kernel<float><<<grid, 256, 0, stream>>>(
        x, EDIM, W1, EDIM + HDIM, /*kw0=*/0, b1, A, HDIM, EDIM);
  }

  // 2) scan: h_t = relu(A_t + h_{t-1} @ W1[:, E:]^T), 2 blocks per cluster
  scan_kernel<<<8, 512, 0, stream>>>(A, W1, Hbf, flags);

  // 3) outs = Hbf @ W2^T + b2 (overwrites the A staging area)
  {
    dim3 grid(BATCH * T_STEPS / 64, ODIM / 64);
    gemm_bias_kernel<bf16><<<grid, 256, 0, stream>>>(
        Hbf, HDIM, W2, HDIM, /*kw0=*/0, b2, out, ODIM, HDIM);
  }

  // 4) h_final tail
  copy_hfinal_kernel<<<(BATCH * HDIM) / 256, 256, 0, stream>>>(
      Hbf, out + (size_t)BATCH * T_STEPS * ODIM);
}